// Round 1
// baseline (738.086 us; speedup 1.0000x reference)
//
#include <hip/hip_runtime.h>
#include <math.h>

#define NN 50000
#define DH 128

// ---------------- utility kernels ----------------
__global__ void zero_int_kernel(int* p, int n) {
  int i = blockIdx.x * blockDim.x + threadIdx.x;
  if (i < n) p[i] = 0;
}

__global__ void zero_f_kernel(float* p, int n) {
  int i = blockIdx.x * blockDim.x + threadIdx.x;
  if (i < n) p[i] = 0.0f;
}

// ---------------- CSR build ----------------
__global__ void hist_kernel(const int* __restrict__ dst, int* __restrict__ cnt, int E) {
  int e = blockIdx.x * blockDim.x + threadIdx.x;
  if (e < E) atomicAdd(&cnt[dst[e]], 1);
}

// single-block scan: cnt (in) -> off (exclusive prefix), cnt overwritten with a
// second copy of the exclusive prefix (used as the fill cursor).
__global__ void scan_kernel(int* __restrict__ cnt, int* __restrict__ off, int n) {
  __shared__ int s[1024];
  int t = threadIdx.x;
  const int CH = (n + 1023) / 1024;
  int begin = t * CH;
  int end = begin + CH; if (end > n) end = n;
  int sum = 0;
  for (int i = begin; i < end && i < n; i++) sum += cnt[i];
  s[t] = sum;
  __syncthreads();
  for (int d = 1; d < 1024; d <<= 1) {
    int v = (t >= d) ? s[t - d] : 0;
    __syncthreads();
    s[t] += v;
    __syncthreads();
  }
  int total = s[1023];
  int base = (t == 0) ? 0 : s[t - 1];
  int running = base;
  for (int i = begin; i < end && i < n; i++) {
    int c = cnt[i];
    off[i] = running;
    cnt[i] = running;   // cursor copy
    running += c;
  }
  if (t == 0) off[n] = total;
}

__global__ void fill_kernel(const int* __restrict__ src, const int* __restrict__ dst,
                            int* __restrict__ cur, int* __restrict__ ssrc, int E) {
  int e = blockIdx.x * blockDim.x + threadIdx.x;
  if (e < E) {
    int p = atomicAdd(&cur[dst[e]], 1);
    ssrc[p] = src[e];
  }
}

// ---------------- fp32 GEMM: C[n,Dout] = A[n,128] @ W[128,Dout] (+bias) ----------------
// block: 256 threads, tile 64 rows x 64 cols, 4x4 per thread.
__global__ __launch_bounds__(256) void gemm_kernel(
    const float* __restrict__ A, const float* __restrict__ W,
    const float* __restrict__ bias, float* __restrict__ C, int n, int Dout) {
  __shared__ float As[64][132];   // padded
  __shared__ float Ws[128][72];   // padded so float4 rows stay 16B aligned
  int t = threadIdx.x;
  int row0 = blockIdx.x * 64, col0 = blockIdx.y * 64;

  // load A tile: 64 rows x 128 cols = 2048 float4 chunks
  for (int idx = t; idx < 2048; idx += 256) {
    int r = idx >> 5, c4 = (idx & 31) * 4;
    float4 v = make_float4(0.f, 0.f, 0.f, 0.f);
    if (row0 + r < n) v = *(const float4*)(A + (size_t)(row0 + r) * 128 + c4);
    As[r][c4] = v.x; As[r][c4 + 1] = v.y; As[r][c4 + 2] = v.z; As[r][c4 + 3] = v.w;
  }
  // load W tile: 128 x 64 = 2048 float4 chunks (128 rows x 16 chunks)
  for (int idx = t; idx < 2048; idx += 256) {
    int k = idx >> 4, c4 = (idx & 15) * 4;
    float4 v = *(const float4*)(W + (size_t)k * Dout + col0 + c4);
    Ws[k][c4] = v.x; Ws[k][c4 + 1] = v.y; Ws[k][c4 + 2] = v.z; Ws[k][c4 + 3] = v.w;
  }
  __syncthreads();

  int tx = t & 15, ty = t >> 4;
  int ty4 = ty * 4, tx4 = tx * 4;
  float acc[4][4];
  if (bias) {
    for (int i = 0; i < 4; i++)
      for (int j = 0; j < 4; j++) acc[i][j] = bias[col0 + tx4 + j];
  } else {
    for (int i = 0; i < 4; i++)
      for (int j = 0; j < 4; j++) acc[i][j] = 0.0f;
  }

#pragma unroll 8
  for (int kk = 0; kk < 128; kk++) {
    float a0 = As[ty4 + 0][kk];
    float a1 = As[ty4 + 1][kk];
    float a2 = As[ty4 + 2][kk];
    float a3 = As[ty4 + 3][kk];
    float4 wv = *(const float4*)(&Ws[kk][tx4]);
    acc[0][0] += a0 * wv.x; acc[0][1] += a0 * wv.y; acc[0][2] += a0 * wv.z; acc[0][3] += a0 * wv.w;
    acc[1][0] += a1 * wv.x; acc[1][1] += a1 * wv.y; acc[1][2] += a1 * wv.z; acc[1][3] += a1 * wv.w;
    acc[2][0] += a2 * wv.x; acc[2][1] += a2 * wv.y; acc[2][2] += a2 * wv.z; acc[2][3] += a2 * wv.w;
    acc[3][0] += a3 * wv.x; acc[3][1] += a3 * wv.y; acc[3][2] += a3 * wv.z; acc[3][3] += a3 * wv.w;
  }

  for (int i = 0; i < 4; i++) {
    int r = row0 + ty4 + i;
    if (r < n) {
      float4 o = make_float4(acc[i][0], acc[i][1], acc[i][2], acc[i][3]);
      *(float4*)(C + (size_t)r * Dout + col0 + tx4) = o;
    }
  }
}

// ---------------- aggregation: h[node] += sum_{j in CSR[node]} yl[ssrc[j]] ----------------
template <int W>
__global__ __launch_bounds__(256) void aggregate_kernel(
    const float* __restrict__ yl, const int* __restrict__ off,
    const int* __restrict__ ssrc, float* __restrict__ h, int n) {
  constexpr int NPB = 256 / W;
  int node = blockIdx.x * NPB + threadIdx.x / W;
  int c = threadIdx.x % W;
  if (node >= n) return;
  int b = off[node], e = off[node + 1];
  float acc = h[(size_t)node * W + c];
  int j = b;
  for (; j + 3 < e; j += 4) {
    int s0 = ssrc[j], s1 = ssrc[j + 1], s2 = ssrc[j + 2], s3 = ssrc[j + 3];
    acc += yl[(size_t)s0 * W + c];
    acc += yl[(size_t)s1 * W + c];
    acc += yl[(size_t)s2 * W + c];
    acc += yl[(size_t)s3 * W + c];
  }
  for (; j < e; j++) acc += yl[(size_t)ssrc[j] * W + c];
  h[(size_t)node * W + c] = acc;
}

// ---------------- BN stats: per-column sum and sumsq over rows ----------------
__global__ __launch_bounds__(256) void bnstats_kernel(
    const float* __restrict__ h, float* __restrict__ stats, int n) {
  int c = threadIdx.x & 127;
  int half = threadIdx.x >> 7;
  float sum = 0.f, sq = 0.f;
  for (int r = blockIdx.x * 2 + half; r < n; r += gridDim.x * 2) {
    float v = h[(size_t)r * 128 + c];
    sum += v; sq += v * v;
  }
  __shared__ float ls[256], lq[256];
  ls[threadIdx.x] = sum; lq[threadIdx.x] = sq;
  __syncthreads();
  if (threadIdx.x < 128) {
    sum = ls[threadIdx.x] + ls[threadIdx.x + 128];
    sq = lq[threadIdx.x] + lq[threadIdx.x + 128];
    atomicAdd(&stats[c], sum);
    atomicAdd(&stats[128 + c], sq);
  }
}

// ---------------- BN apply + exact GELU ----------------
__global__ __launch_bounds__(256) void bnapply_kernel(
    const float* __restrict__ hin, const float* __restrict__ stats,
    const float* __restrict__ g, const float* __restrict__ be,
    float* __restrict__ hout, int n) {
  int idx = blockIdx.x * blockDim.x + threadIdx.x;
  if (idx >= n * 128) return;
  int c = idx & 127;
  float inv_n = 1.0f / (float)NN;
  float mu = stats[c] * inv_n;
  float var = stats[128 + c] * inv_n - mu * mu;
  float sc = rsqrtf(var + 1e-5f) * g[c];
  float v = (hin[idx] - mu) * sc + be[c];
  hout[idx] = 0.5f * v * (1.0f + erff(v * 0.70710678118654752f));
}

extern "C" void kernel_launch(void* const* d_in, const int* in_sizes, int n_in,
                              void* d_out, int out_size, void* d_ws, size_t ws_size,
                              hipStream_t stream) {
  const float* x   = (const float*)d_in[0];
  const int* edge  = (const int*)d_in[1];
  const int E = in_sizes[1] / 2;
  const int* esrc = edge;
  const int* edst = edge + E;
  const float* W0l = (const float*)d_in[2];
  const float* W0r = (const float*)d_in[3];
  const float* b0  = (const float*)d_in[4];
  const float* g0  = (const float*)d_in[5];
  const float* be0 = (const float*)d_in[6];
  const float* W1l = (const float*)d_in[7];
  const float* W1r = (const float*)d_in[8];
  const float* b1  = (const float*)d_in[9];
  const float* g1  = (const float*)d_in[10];
  const float* be1 = (const float*)d_in[11];
  const float* W2l = (const float*)d_in[12];
  const float* W2r = (const float*)d_in[13];
  const float* b2  = (const float*)d_in[14];
  float* out = (float*)d_out;

  const int n = NN;
  // ---- workspace layout (all 16B aligned) ----
  int* off  = (int*)d_ws;            // n+1 ints (use 50304 slots)
  int* cur  = off + 50304;           // n ints
  int* ssrc = cur + 50304;           // E ints
  float* yl = (float*)(ssrc + 800064);          // n*128 floats
  float* ha = yl + (size_t)n * 128;             // n*128
  float* hb = ha + (size_t)n * 128;             // n*128
  float* stats = hb + (size_t)n * 128;          // 256

  const int TB = 256;
  dim3 gemm_grid2((n + 63) / 64, 2);
  dim3 gemm_grid1((n + 63) / 64, 1);

  // ---- CSR build (per launch: ws is re-poisoned) ----
  zero_int_kernel<<<(n + TB - 1) / TB, TB, 0, stream>>>(cur, n);
  hist_kernel<<<(E + TB - 1) / TB, TB, 0, stream>>>(edst, cur, E);
  scan_kernel<<<1, 1024, 0, stream>>>(cur, off, n);
  fill_kernel<<<(E + TB - 1) / TB, TB, 0, stream>>>(esrc, edst, cur, ssrc, E);

  // ---- layer 0 ----
  gemm_kernel<<<gemm_grid2, TB, 0, stream>>>(x, W0l, nullptr, yl, n, 128);
  gemm_kernel<<<gemm_grid2, TB, 0, stream>>>(x, W0r, b0, ha, n, 128);
  aggregate_kernel<128><<<n / 2, TB, 0, stream>>>(yl, off, ssrc, ha, n);
  zero_f_kernel<<<1, TB, 0, stream>>>(stats, 256);
  bnstats_kernel<<<256, TB, 0, stream>>>(ha, stats, n);
  bnapply_kernel<<<(n * 128 + TB - 1) / TB, TB, 0, stream>>>(ha, stats, g0, be0, hb, n);

  // ---- layer 1 ----
  gemm_kernel<<<gemm_grid2, TB, 0, stream>>>(hb, W1l, nullptr, yl, n, 128);
  gemm_kernel<<<gemm_grid2, TB, 0, stream>>>(hb, W1r, b1, ha, n, 128);
  aggregate_kernel<128><<<n / 2, TB, 0, stream>>>(yl, off, ssrc, ha, n);
  zero_f_kernel<<<1, TB, 0, stream>>>(stats, 256);
  bnstats_kernel<<<256, TB, 0, stream>>>(ha, stats, n);
  bnapply_kernel<<<(n * 128 + TB - 1) / TB, TB, 0, stream>>>(ha, stats, g1, be1, hb, n);

  // ---- layer 2 (no BN/GELU) ----
  gemm_kernel<<<gemm_grid1, TB, 0, stream>>>(hb, W2l, nullptr, yl, n, 64);
  gemm_kernel<<<gemm_grid1, TB, 0, stream>>>(hb, W2r, b2, out, n, 64);
  aggregate_kernel<64><<<n / 4, TB, 0, stream>>>(yl, off, ssrc, out, n);
}

// Round 2
// 435.703 us; speedup vs baseline: 1.6940x; 1.6940x over previous
//
#include <hip/hip_runtime.h>
#include <math.h>

#define NN 50000

typedef unsigned short u16;
typedef short bf16x8 __attribute__((ext_vector_type(8)));
typedef float floatx4 __attribute__((ext_vector_type(4)));

__device__ inline u16 f32_to_bf16(float f) {
  unsigned u = __builtin_bit_cast(unsigned, f);
  u += 0x7fffu + ((u >> 16) & 1u);   // round-to-nearest-even
  return (u16)(u >> 16);
}
__device__ inline float bf16_to_f32(u16 h) {
  unsigned u = ((unsigned)h) << 16;
  return __builtin_bit_cast(float, u);
}

// ---------------- zero cur + stats ----------------
__global__ void zero_misc_kernel(int* __restrict__ cur, float* __restrict__ stats, int n) {
  int i = blockIdx.x * blockDim.x + threadIdx.x;
  if (i < n) cur[i] = 0;
  if (i < 512) stats[i] = 0.0f;
}

// ---------------- CSR build ----------------
__global__ void hist_kernel(const int* __restrict__ dst, int* __restrict__ cnt, int E) {
  int e = blockIdx.x * blockDim.x + threadIdx.x;
  if (e < E) atomicAdd(&cnt[dst[e]], 1);
}

// per-256-block exclusive scan; ex[i] = exclusive within block; btot[b] = block sum
__global__ __launch_bounds__(256) void scan1_kernel(const int* __restrict__ cnt, int* __restrict__ ex,
                                                    int* __restrict__ btot, int n) {
  __shared__ int s[256];
  int t = threadIdx.x, i = blockIdx.x * 256 + t;
  int v = (i < n) ? cnt[i] : 0;
  s[t] = v;
  __syncthreads();
  for (int d = 1; d < 256; d <<= 1) {
    int u = (t >= d) ? s[t - d] : 0;
    __syncthreads();
    s[t] += u;
    __syncthreads();
  }
  if (i < n) ex[i] = s[t] - v;
  if (t == 255) btot[blockIdx.x] = s[255];
}

// scan the (<=256) block totals; boff[b] = exclusive; off[n] = grand total
__global__ __launch_bounds__(256) void scan2_kernel(const int* __restrict__ btot, int* __restrict__ boff,
                                                    int* __restrict__ off_n, int nb) {
  __shared__ int s[256];
  int t = threadIdx.x;
  int v = (t < nb) ? btot[t] : 0;
  s[t] = v;
  __syncthreads();
  for (int d = 1; d < 256; d <<= 1) {
    int u = (t >= d) ? s[t - d] : 0;
    __syncthreads();
    s[t] += u;
    __syncthreads();
  }
  boff[t] = s[t] - v;
  if (t == 255) *off_n = s[255];
}

__global__ __launch_bounds__(256) void scan3_kernel(int* __restrict__ off, int* __restrict__ cur,
                                                    const int* __restrict__ boff, int n) {
  int i = blockIdx.x * 256 + threadIdx.x;
  if (i < n) {
    int v = off[i] + boff[blockIdx.x];
    off[i] = v;
    cur[i] = v;
  }
}

__global__ void fill_kernel(const int* __restrict__ src, const int* __restrict__ dst,
                            int* __restrict__ cur, int* __restrict__ ssrc, int E) {
  int e = blockIdx.x * blockDim.x + threadIdx.x;
  if (e < E) {
    int p = atomicAdd(&cur[dst[e]], 1);
    ssrc[p] = src[e];
  }
}

// ---------------- converts ----------------
__global__ void convert_x_kernel(const float* __restrict__ x, u16* __restrict__ xb, int total4) {
  int i = blockIdx.x * blockDim.x + threadIdx.x;
  if (i >= total4) return;
  float4 v = *(const float4*)(x + (size_t)i * 4);
  ushort4 o;
  o.x = f32_to_bf16(v.x); o.y = f32_to_bf16(v.y); o.z = f32_to_bf16(v.z); o.w = f32_to_bf16(v.w);
  *(ushort4*)(xb + (size_t)i * 4) = o;
}

// transpose+convert all 6 weights: W[k][nc] fp32 -> Wt[nc][128] bf16 (each slot 16384 u16)
__global__ void convert_w_kernel(const float* W0l, const float* W0r, const float* W1l,
                                 const float* W1r, const float* W2l, const float* W2r,
                                 u16* __restrict__ Wt) {
  int w = blockIdx.x;
  const float* src;
  int ncols;
  switch (w) {
    case 0: src = W0l; ncols = 128; break;
    case 1: src = W0r; ncols = 128; break;
    case 2: src = W1l; ncols = 128; break;
    case 3: src = W1r; ncols = 128; break;
    case 4: src = W2l; ncols = 64; break;
    default: src = W2r; ncols = 64; break;
  }
  u16* dst = Wt + w * 16384;
  int total = ncols * 128;
  for (int idx = blockIdx.y * 1024 + threadIdx.x; idx < total; idx += 1024) {
    // only 4 y-blocks of 1024 needed per weight
  }
  int idx = blockIdx.y * 1024 + threadIdx.x;
  for (int k = 0; k < 4; k++, idx += 256) {
    if (idx < total) {
      int nc = idx >> 7, kk = idx & 127;       // dst[nc][kk]
      dst[nc * 128 + kk] = f32_to_bf16(src[kk * ncols + nc]);
    }
  }
}

// ---------------- dual bf16-MFMA GEMM ----------------
// A: [n][128] bf16. WtL: [NL][128] bf16 (transposed), WtR: [NR][128].
// Cl: [n][NL] bf16 (no bias), Cr: [n][NR] fp32 (+bias).
// MFMA 16x16x32 bf16. A-frag: A[m=lane&15][k=quad*8+j]. B-frag: B[nc=lane&15][k=quad*8+j]
// (from transposed W). C/D: col=lane&15, row=quad*4+reg (m89-verified mapping).
template <int NL, int NR>
__global__ __launch_bounds__(256) void gemm_dual_kernel(
    const u16* __restrict__ A, const u16* __restrict__ WtL, const u16* __restrict__ WtR,
    const float* __restrict__ bias, u16* __restrict__ Cl, float* __restrict__ Cr, int n) {
  constexpr int NT = (NL + NR) / 16;
  constexpr int NTL = NL / 16;
  __shared__ u16 Wlds[NL + NR][136];   // +8 pad: b128 reads land 2-way on banks (free)
  int t = threadIdx.x;

  // stage both W into LDS, 16B chunks
  for (int idx = t; idx < (NL + NR) * 16; idx += 256) {
    int rw = idx >> 4, c8 = (idx & 15) * 8;
    const u16* srcp = (rw < NL) ? (WtL + rw * 128 + c8) : (WtR + (rw - NL) * 128 + c8);
    *(float4*)(&Wlds[rw][c8]) = *(const float4*)srcp;
  }
  __syncthreads();

  int wave = t >> 6, lane = t & 63;
  int quad = lane >> 4, l16 = lane & 15;
  int row0 = blockIdx.x * 64 + wave * 16;
  int arow = row0 + l16;
  bool rowok = arow < n;
  const u16* Ap = A + (size_t)arow * 128 + quad * 8;

  floatx4 acc[NT];
#pragma unroll
  for (int i = 0; i < NT; i++) acc[i] = (floatx4){0.f, 0.f, 0.f, 0.f};

#pragma unroll
  for (int kk = 0; kk < 4; kk++) {
    bf16x8 a;
    if (rowok) a = *(const bf16x8*)(Ap + kk * 32);
    else a = (bf16x8){0, 0, 0, 0, 0, 0, 0, 0};
#pragma unroll
    for (int tile = 0; tile < NT; tile++) {
      bf16x8 b = *(const bf16x8*)(&Wlds[tile * 16 + l16][kk * 32 + quad * 8]);
      acc[tile] = __builtin_amdgcn_mfma_f32_16x16x32_bf16(a, b, acc[tile], 0, 0, 0);
    }
  }

#pragma unroll
  for (int tile = 0; tile < NT; tile++) {
#pragma unroll
    for (int r = 0; r < 4; r++) {
      int row = row0 + quad * 4 + r;
      if (row < n) {
        float v = acc[tile][r];
        if (tile < NTL) {
          int col = tile * 16 + l16;
          Cl[(size_t)row * NL + col] = f32_to_bf16(v);
        } else {
          int col = (tile - NTL) * 16 + l16;
          Cr[(size_t)row * NR + col] = v + bias[col];
        }
      }
    }
  }
}

// ---------------- aggregation: h[node] += sum yl_bf16[ssrc[j]] ----------------
template <int D>
__global__ __launch_bounds__(256) void aggregate_kernel(
    const u16* __restrict__ yl, const int* __restrict__ off,
    const int* __restrict__ ssrc, float* __restrict__ h, int n) {
  constexpr int TPN = D / 4;             // threads per node (4 cols each)
  constexpr int NPB = 256 / TPN;
  int node = blockIdx.x * NPB + threadIdx.x / TPN;
  int c4 = (threadIdx.x % TPN) * 4;
  if (node >= n) return;
  int b = off[node], e = off[node + 1];
  float4 acc = *(const float4*)(h + (size_t)node * D + c4);
  int j = b;
  for (; j + 3 < e; j += 4) {
    int s0 = ssrc[j], s1 = ssrc[j + 1], s2 = ssrc[j + 2], s3 = ssrc[j + 3];
    ushort4 v0 = *(const ushort4*)(yl + (size_t)s0 * D + c4);
    ushort4 v1 = *(const ushort4*)(yl + (size_t)s1 * D + c4);
    ushort4 v2 = *(const ushort4*)(yl + (size_t)s2 * D + c4);
    ushort4 v3 = *(const ushort4*)(yl + (size_t)s3 * D + c4);
    acc.x += bf16_to_f32(v0.x) + bf16_to_f32(v1.x) + bf16_to_f32(v2.x) + bf16_to_f32(v3.x);
    acc.y += bf16_to_f32(v0.y) + bf16_to_f32(v1.y) + bf16_to_f32(v2.y) + bf16_to_f32(v3.y);
    acc.z += bf16_to_f32(v0.z) + bf16_to_f32(v1.z) + bf16_to_f32(v2.z) + bf16_to_f32(v3.z);
    acc.w += bf16_to_f32(v0.w) + bf16_to_f32(v1.w) + bf16_to_f32(v2.w) + bf16_to_f32(v3.w);
  }
  for (; j < e; j++) {
    int s0 = ssrc[j];
    ushort4 v0 = *(const ushort4*)(yl + (size_t)s0 * D + c4);
    acc.x += bf16_to_f32(v0.x); acc.y += bf16_to_f32(v0.y);
    acc.z += bf16_to_f32(v0.z); acc.w += bf16_to_f32(v0.w);
  }
  *(float4*)(h + (size_t)node * D + c4) = acc;
}

// ---------------- BN stats ----------------
__global__ __launch_bounds__(256) void bnstats_kernel(
    const float* __restrict__ h, float* __restrict__ stats, int n) {
  int c = threadIdx.x & 127;
  int half = threadIdx.x >> 7;
  float sum = 0.f, sq = 0.f;
  for (int r = blockIdx.x * 2 + half; r < n; r += gridDim.x * 2) {
    float v = h[(size_t)r * 128 + c];
    sum += v; sq += v * v;
  }
  __shared__ float ls[256], lq[256];
  ls[threadIdx.x] = sum; lq[threadIdx.x] = sq;
  __syncthreads();
  if (threadIdx.x < 128) {
    sum = ls[threadIdx.x] + ls[threadIdx.x + 128];
    sq = lq[threadIdx.x] + lq[threadIdx.x + 128];
    atomicAdd(&stats[c], sum);
    atomicAdd(&stats[128 + c], sq);
  }
}

// ---------------- BN apply + exact GELU -> bf16 ----------------
__global__ __launch_bounds__(256) void bnapply_kernel(
    const float* __restrict__ hin, const float* __restrict__ stats,
    const float* __restrict__ g, const float* __restrict__ be,
    u16* __restrict__ hout, int n) {
  int idx = blockIdx.x * blockDim.x + threadIdx.x;
  if (idx >= n * 128) return;
  int c = idx & 127;
  float inv_n = 1.0f / (float)NN;
  float mu = stats[c] * inv_n;
  float var = stats[128 + c] * inv_n - mu * mu;
  float sc = rsqrtf(var + 1e-5f) * g[c];
  float v = (hin[idx] - mu) * sc + be[c];
  float gelu = 0.5f * v * (1.0f + erff(v * 0.70710678118654752f));
  hout[idx] = f32_to_bf16(gelu);
}

extern "C" void kernel_launch(void* const* d_in, const int* in_sizes, int n_in,
                              void* d_out, int out_size, void* d_ws, size_t ws_size,
                              hipStream_t stream) {
  const float* x   = (const float*)d_in[0];
  const int* edge  = (const int*)d_in[1];
  const int E = in_sizes[1] / 2;
  const int* esrc = edge;
  const int* edst = edge + E;
  const float* W0l = (const float*)d_in[2];
  const float* W0r = (const float*)d_in[3];
  const float* b0  = (const float*)d_in[4];
  const float* g0  = (const float*)d_in[5];
  const float* be0 = (const float*)d_in[6];
  const float* W1l = (const float*)d_in[7];
  const float* W1r = (const float*)d_in[8];
  const float* b1  = (const float*)d_in[9];
  const float* g1  = (const float*)d_in[10];
  const float* be1 = (const float*)d_in[11];
  const float* W2l = (const float*)d_in[12];
  const float* W2r = (const float*)d_in[13];
  const float* b2  = (const float*)d_in[14];
  float* out = (float*)d_out;

  const int n = NN;
  // ---- workspace layout (all 16B aligned) ----
  int* off   = (int*)d_ws;              // 50304
  int* cur   = off + 50304;             // 50304
  int* ssrc  = cur + 50304;             // 800064
  int* btot  = ssrc + 800064;           // 256
  int* boff  = btot + 256;              // 256
  float* stats = (float*)(boff + 256);  // 512 (stats0 | stats1)
  u16* xb  = (u16*)(stats + 512);       // n*128
  u16* Wt  = xb + (size_t)n * 128;      // 6*16384
  u16* ylb = Wt + 6 * 16384;            // n*128
  float* ha = (float*)(ylb + (size_t)n * 128);  // n*128 fp32
  u16* hb  = (u16*)(ha + (size_t)n * 128);      // n*128 bf16
  float* stats0 = stats;
  float* stats1 = stats + 256;

  const int TB = 256;
  const int NB1 = (n + 255) / 256;      // 196 scan blocks

  // ---- CSR build ----
  zero_misc_kernel<<<NB1, TB, 0, stream>>>(cur, stats, n);
  hist_kernel<<<(E + TB - 1) / TB, TB, 0, stream>>>(edst, cur, E);
  scan1_kernel<<<NB1, TB, 0, stream>>>(cur, off, btot, n);
  scan2_kernel<<<1, TB, 0, stream>>>(btot, boff, off + n, NB1);
  scan3_kernel<<<NB1, TB, 0, stream>>>(off, cur, boff, n);
  fill_kernel<<<(E + TB - 1) / TB, TB, 0, stream>>>(esrc, edst, cur, ssrc, E);

  // ---- converts ----
  convert_x_kernel<<<(n * 128 / 4 + TB - 1) / TB, TB, 0, stream>>>(x, xb, n * 128 / 4);
  convert_w_kernel<<<dim3(6, 16), TB, 0, stream>>>(W0l, W0r, W1l, W1r, W2l, W2r, Wt);

  const int GB = (n + 63) / 64;         // gemm row-tile blocks

  // ---- layer 0 ----
  gemm_dual_kernel<128, 128><<<GB, TB, 0, stream>>>(xb, Wt + 0 * 16384, Wt + 1 * 16384, b0, ylb, ha, n);
  aggregate_kernel<128><<<(n + 7) / 8, TB, 0, stream>>>(ylb, off, ssrc, ha, n);
  bnstats_kernel<<<256, TB, 0, stream>>>(ha, stats0, n);
  bnapply_kernel<<<(n * 128 + TB - 1) / TB, TB, 0, stream>>>(ha, stats0, g0, be0, hb, n);

  // ---- layer 1 ----
  gemm_dual_kernel<128, 128><<<GB, TB, 0, stream>>>(hb, Wt + 2 * 16384, Wt + 3 * 16384, b1, ylb, ha, n);
  aggregate_kernel<128><<<(n + 7) / 8, TB, 0, stream>>>(ylb, off, ssrc, ha, n);
  bnstats_kernel<<<256, TB, 0, stream>>>(ha, stats1, n);
  bnapply_kernel<<<(n * 128 + TB - 1) / TB, TB, 0, stream>>>(ha, stats1, g1, be1, hb, n);

  // ---- layer 2 ----
  gemm_dual_kernel<64, 64><<<GB, TB, 0, stream>>>(hb, Wt + 4 * 16384, Wt + 5 * 16384, b2, ylb, out, n);
  aggregate_kernel<64><<<(n + 15) / 16, TB, 0, stream>>>(ylb, off, ssrc, out, n);
}